// Round 1
// baseline (774.591 us; speedup 1.0000x reference)
//
#include <hip/hip_runtime.h>
#include <math.h>

// Problem constants (B=8, T=4096, D=1024, G=2, N=320, Cd=512)
#define M_ROWS 32768   // B*T
#define KDIM   1024    // D
#define GN     640     // G*N
#define NGRP   2
#define NCODES 320
#define CD     512

#define BM 64          // rows per block
#define BK 16          // k-tile

// Block: 256 threads = 16 (ty: row groups) x 16 (tx: col groups)
// Each thread: 4 rows (r = ty*4+i) x 20 cols (c = tx + 16*j), one group g per block.
__global__ __launch_bounds__(256) void gemm_argmax_gather(
    const float* __restrict__ x,        // [M, K]
    const float* __restrict__ gumbel,   // [M, G, N]
    const float* __restrict__ codebook, // [G, N, CD]
    const float* __restrict__ W,        // [K, GN]
    const float* __restrict__ bias,     // [GN]
    float* __restrict__ out,            // [M, G*CD] (=[B,T,D])
    int* __restrict__ counts)           // [G*N]
{
    __shared__ float xs[BM][BK + 1];      // +1 pad: breaks same-bank stride
    __shared__ float wsm[BK][NCODES];     // 16x320 fp32 = 20 KB
    __shared__ int   idx_s[BM];

    const int tid  = threadIdx.x;
    const int g    = blockIdx.y;
    const int row0 = blockIdx.x * BM;
    const int ty   = tid >> 4;   // 0..15
    const int tx   = tid & 15;   // 0..15

    float acc[4][20];
#pragma unroll
    for (int i = 0; i < 4; ++i)
#pragma unroll
        for (int j = 0; j < 20; ++j) acc[i][j] = 0.0f;

    const int xrow = tid >> 2;  // 0..63
    const int xq   = tid & 3;   // float4 slot within row's k-tile

    for (int k0 = 0; k0 < KDIM; k0 += BK) {
        // ---- stage x tile: 64 rows x 16 k (one float4 per thread)
        float4 xv = *reinterpret_cast<const float4*>(
            &x[(size_t)(row0 + xrow) * KDIM + k0 + xq * 4]);
        xs[xrow][xq * 4 + 0] = xv.x;
        xs[xrow][xq * 4 + 1] = xv.y;
        xs[xrow][xq * 4 + 2] = xv.z;
        xs[xrow][xq * 4 + 3] = xv.w;
        // ---- stage W tile: 16 k-rows x 320 cols (5 float4 per thread)
#pragma unroll
        for (int s = 0; s < 5; ++s) {
            int f4 = tid + 256 * s;          // 0..1279
            int kk = f4 / 80;                // 80 float4 per k-row
            int c4 = f4 % 80;
            float4 wv = *reinterpret_cast<const float4*>(
                &W[(size_t)(k0 + kk) * GN + g * NCODES + c4 * 4]);
            *reinterpret_cast<float4*>(&wsm[kk][c4 * 4]) = wv;
        }
        __syncthreads();

#pragma unroll
        for (int kk = 0; kk < BK; ++kk) {
            float a[4], b[20];
#pragma unroll
            for (int i = 0; i < 4; ++i) a[i] = xs[ty * 4 + i][kk];
#pragma unroll
            for (int j = 0; j < 20; ++j) b[j] = wsm[kk][tx + 16 * j];
#pragma unroll
            for (int i = 0; i < 4; ++i)
#pragma unroll
                for (int j = 0; j < 20; ++j)
                    acc[i][j] = fmaf(a[i], b[j], acc[i][j]);
        }
        __syncthreads();
    }

    // ---- epilogue: + bias + gumbel, argmax over the 320 cols of this group
#pragma unroll
    for (int i = 0; i < 4; ++i) {
        const int lr = ty * 4 + i;
        const int r  = row0 + lr;
        float best = -INFINITY;
        int   bidx = 0;
#pragma unroll
        for (int j = 0; j < 20; ++j) {
            int c = tx + 16 * j;
            float v = acc[i][j] + bias[g * NCODES + c]
                    + gumbel[((size_t)r * NGRP + g) * NCODES + c];
            if (v > best) { best = v; bidx = c; }  // j ascending => first-max kept
        }
        // reduce across the 16 tx lanes (contiguous lanes within the wave)
#pragma unroll
        for (int m = 1; m < 16; m <<= 1) {
            float ov = __shfl_xor(best, m, 64);
            int   oi = __shfl_xor(bidx, m, 64);
            if (ov > best || (ov == best && oi < bidx)) { best = ov; bidx = oi; }
        }
        if (tx == 0) {
            idx_s[lr] = bidx;
            atomicAdd(&counts[g * NCODES + bidx], 1);
        }
    }
    __syncthreads();

    // ---- gather: out[r, g*CD : (g+1)*CD] = codebook[g, idx, :]
    // 64 rows x 128 float4 = 8192 float4; 32 per thread, coalesced writes.
#pragma unroll
    for (int s = 0; s < 32; ++s) {
        int f4 = tid + 256 * s;
        int lr = f4 >> 7;          // /128
        int c4 = f4 & 127;
        int n  = idx_s[lr];
        float4 cv = *reinterpret_cast<const float4*>(
            &codebook[((size_t)g * NCODES + n) * CD + c4 * 4]);
        size_t off = (size_t)(row0 + lr) * (NGRP * CD) + (size_t)g * CD + c4 * 4;
        *reinterpret_cast<float4*>(&out[off]) = cv;
    }
}

__global__ void zero_counts(int* __restrict__ counts) {
    int i = threadIdx.x + blockIdx.x * blockDim.x;
    if (i < GN) counts[i] = 0;
}

__global__ void loss_kernel(const int* __restrict__ counts, float* __restrict__ out_loss) {
    __shared__ float red[256];
    float sum = 0.0f;
    for (int i = threadIdx.x; i < GN; i += 256) {
        float avg = (float)counts[i] * (1.0f / (float)M_ROWS);
        sum += avg * logf(avg + 1e-7f);
    }
    red[threadIdx.x] = sum;
    __syncthreads();
    for (int s = 128; s > 0; s >>= 1) {
        if (threadIdx.x < s) red[threadIdx.x] += red[threadIdx.x + s];
        __syncthreads();
    }
    if (threadIdx.x == 0) out_loss[0] = -red[0] * (1.0f / (float)NGRP);
}

extern "C" void kernel_launch(void* const* d_in, const int* in_sizes, int n_in,
                              void* d_out, int out_size, void* d_ws, size_t ws_size,
                              hipStream_t stream) {
    const float* x        = (const float*)d_in[0];
    const float* gumbel   = (const float*)d_in[1];
    const float* codebook = (const float*)d_in[2];
    const float* W        = (const float*)d_in[3];
    const float* bias     = (const float*)d_in[4];
    float* out = (float*)d_out;
    int* counts = (int*)d_ws;   // 640 ints

    zero_counts<<<dim3(3), dim3(256), 0, stream>>>(counts);
    dim3 grid(M_ROWS / BM, NGRP);
    gemm_argmax_gather<<<grid, dim3(256), 0, stream>>>(
        x, gumbel, codebook, W, bias, out, counts);
    loss_kernel<<<dim3(1), dim3(256), 0, stream>>>(
        counts, out + (size_t)M_ROWS * KDIM);
}

// Round 2
// 220.691 us; speedup vs baseline: 3.5098x; 3.5098x over previous
//
#include <hip/hip_runtime.h>
#include <math.h>

// Problem constants (B=8, T=4096, D=1024, G=2, N=320, Cd=512)
#define M_ROWS 32768   // B*T
#define KDIM   1024    // D
#define GN     640     // G*N
#define NGRP   2
#define NCODES 320
#define CD     512

#define BM 32          // rows per block
#define BK 64          // k-tile
#define NIT (KDIM / BK)  // 16

typedef __attribute__((ext_vector_type(8))) short bf16x8;   // 8 bf16 = 4 VGPR
typedef __attribute__((ext_vector_type(4))) float f32x4;

__device__ __forceinline__ unsigned short f2bf(float f) {
    unsigned u = __builtin_bit_cast(unsigned, f);
    return (unsigned short)((u + 0x7FFFu + ((u >> 16) & 1u)) >> 16);  // RNE
}
__device__ __forceinline__ unsigned pk2(float lo, float hi) {
    return (unsigned)f2bf(lo) | ((unsigned)f2bf(hi) << 16);
}

// ---- prepass: W[K][GN] fp32  ->  Wt[GN][K] bf16 (so B-fragments are K-contiguous)
__global__ __launch_bounds__(256) void wt_kernel(const float* __restrict__ W,
                                                 unsigned short* __restrict__ Wt) {
    __shared__ float tile[32][33];
    const int n0 = blockIdx.x * 32, k0 = blockIdx.y * 32;
    const int tx = threadIdx.x & 31, ty = threadIdx.x >> 5;  // ty 0..7
#pragma unroll
    for (int i = 0; i < 4; ++i) {
        int kk = ty + 8 * i;
        tile[kk][tx] = W[(size_t)(k0 + kk) * GN + n0 + tx];
    }
    __syncthreads();
#pragma unroll
    for (int i = 0; i < 4; ++i) {
        int nn = ty + 8 * i;
        Wt[(size_t)(n0 + nn) * KDIM + k0 + tx] = f2bf(tile[tx][nn]);
    }
}

__global__ void zero_counts(int* __restrict__ counts) {
    int i = threadIdx.x + blockIdx.x * blockDim.x;
    if (i < GN) counts[i] = 0;
}

// ---- fused MFMA GEMM + argmax + gather
// Block: 256 threads = 4 waves. Wave w owns cols w*160..w*160+159 (waves 0,1 = group 0,
// waves 2,3 = group 1), rows row0..row0+31 (2 M-fragments of 16).
__global__ __launch_bounds__(256) void gemm_argmax_gather(
    const float* __restrict__ x,              // [M, K] fp32
    const float* __restrict__ gumbel,         // [M, GN] fp32
    const float* __restrict__ codebook,       // [G, N, CD] fp32
    const unsigned short* __restrict__ Wt,    // [GN, K] bf16
    const float* __restrict__ bias,           // [GN]
    float* __restrict__ out,                  // [M, G*CD] fp32 (+ loss slot appended)
    int* __restrict__ counts)                 // [GN]
{
    __shared__ __align__(16) unsigned short xs[2][BM][BK];  // 8 KB, XOR-swizzled rows
    __shared__ float pv[NGRP][2][BM];
    __shared__ int   pi[NGRP][2][BM];
    __shared__ int   idx_s[NGRP][BM];

    const int tid  = threadIdx.x;
    const int wid  = tid >> 6;        // 0..3 (N-wave)
    const int lane = tid & 63;
    const int l15  = lane & 15;
    const int l4   = lane >> 4;       // 0..3
    const int row0 = blockIdx.x * BM;

    f32x4 acc[2][10];
#pragma unroll
    for (int mf = 0; mf < 2; ++mf)
#pragma unroll
        for (int nf = 0; nf < 10; ++nf) acc[mf][nf] = (f32x4){0.f, 0.f, 0.f, 0.f};

    // staging geometry: thread -> (row, 8-elem k-slot)
    const int srow  = tid >> 3;   // 0..31
    const int sslot = tid & 7;    // 0..7  (slot of 8 bf16 = 16 B in the 128 B LDS row)
    const int swslot = sslot ^ (srow & 7);          // write-side XOR swizzle
    const float* xsrc = &x[(size_t)(row0 + srow) * KDIM + sslot * 8];

    // prologue: stage k-tile 0
    {
        float4 a = *reinterpret_cast<const float4*>(xsrc);
        float4 b = *reinterpret_cast<const float4*>(xsrc + 4);
        union { bf16x8 v; unsigned u[4]; } w;
        w.u[0] = pk2(a.x, a.y); w.u[1] = pk2(a.z, a.w);
        w.u[2] = pk2(b.x, b.y); w.u[3] = pk2(b.z, b.w);
        *reinterpret_cast<bf16x8*>(&xs[0][srow][swslot * 8]) = w.v;
    }

    for (int it = 0; it < NIT; ++it) {
        __syncthreads();
        const int buf = it & 1;
        // issue next tile's global loads early (hide HBM under MFMA)
        float4 na, nb;
        if (it + 1 < NIT) {
            na = *reinterpret_cast<const float4*>(xsrc + (it + 1) * BK);
            nb = *reinterpret_cast<const float4*>(xsrc + (it + 1) * BK + 4);
        }
#pragma unroll
        for (int ks = 0; ks < 2; ++ks) {
            bf16x8 afr[2];
#pragma unroll
            for (int mf = 0; mf < 2; ++mf) {
                int row  = mf * 16 + l15;
                int slot = (ks * 4 + l4) ^ (row & 7);   // read-side XOR swizzle
                afr[mf] = *reinterpret_cast<const bf16x8*>(&xs[buf][row][slot * 8]);
            }
            const int kk = it * BK + ks * 32 + l4 * 8;
#pragma unroll
            for (int nf = 0; nf < 10; ++nf) {
                int c = wid * 160 + nf * 16 + l15;
                bf16x8 bfr = *reinterpret_cast<const bf16x8*>(&Wt[(size_t)c * KDIM + kk]);
                acc[0][nf] = __builtin_amdgcn_mfma_f32_16x16x32_bf16(afr[0], bfr, acc[0][nf], 0, 0, 0);
                acc[1][nf] = __builtin_amdgcn_mfma_f32_16x16x32_bf16(afr[1], bfr, acc[1][nf], 0, 0, 0);
            }
        }
        if (it + 1 < NIT) {
            union { bf16x8 v; unsigned u[4]; } w;
            w.u[0] = pk2(na.x, na.y); w.u[1] = pk2(na.z, na.w);
            w.u[2] = pk2(nb.x, nb.y); w.u[3] = pk2(nb.z, nb.w);
            *reinterpret_cast<bf16x8*>(&xs[buf ^ 1][srow][swslot * 8]) = w.v;
        }
    }

    // ---- epilogue: + bias + gumbel, argmax per row within this wave's 160 cols
    // C/D layout (m89): col = l15, row-in-frag = l4*4 + reg
#pragma unroll
    for (int mf = 0; mf < 2; ++mf) {
#pragma unroll
        for (int j = 0; j < 4; ++j) {
            const int lr = mf * 16 + l4 * 4 + j;
            const size_t grow = (size_t)(row0 + lr) * GN;
            float best = -INFINITY;
            int bidx = 0;
#pragma unroll
            for (int nf = 0; nf < 10; ++nf) {
                int c = wid * 160 + nf * 16 + l15;
                float v = acc[mf][nf][j] + bias[c] + gumbel[grow + c];
                if (v > best) { best = v; bidx = c; }   // nf ascending -> first max kept
            }
#pragma unroll
            for (int m = 1; m < 16; m <<= 1) {
                float ov = __shfl_xor(best, m, 64);
                int   oi = __shfl_xor(bidx, m, 64);
                if (ov > best || (ov == best && oi < bidx)) { best = ov; bidx = oi; }
            }
            if (l15 == 0) {
                pv[wid >> 1][wid & 1][lr] = best;
                pi[wid >> 1][wid & 1][lr] = bidx;
            }
        }
    }
    __syncthreads();

    // combine the two half-waves per group; half 1's cols are all > half 0's,
    // so strict > keeps the lower index on ties (matches np.argmax).
    if (tid < NGRP * BM) {
        const int g = tid >> 5, lr = tid & 31;
        float v0 = pv[g][0][lr], v1 = pv[g][1][lr];
        int   i0 = pi[g][0][lr], i1 = pi[g][1][lr];
        int bi = (v1 > v0) ? i1 : i0;
        int n  = bi - g * NCODES;
        idx_s[g][lr] = n;
        atomicAdd(&counts[g * NCODES + n], 1);
    }
    __syncthreads();

    // ---- gather: 32 rows x 1024 floats = 8192 float4, coalesced writes
#pragma unroll
    for (int s = 0; s < 32; ++s) {
        int fi = tid + 256 * s;
        int lr = fi >> 8;          // /256 float4 per row
        int q  = fi & 255;
        int g  = q >> 7;
        int n  = idx_s[g][lr];
        float4 cv = *reinterpret_cast<const float4*>(
            &codebook[((size_t)g * NCODES + n) * CD + (q & 127) * 4]);
        *reinterpret_cast<float4*>(&out[(size_t)(row0 + lr) * KDIM + q * 4]) = cv;
    }
}

__global__ void loss_kernel(const int* __restrict__ counts, float* __restrict__ out_loss) {
    __shared__ float red[256];
    float sum = 0.0f;
    for (int i = threadIdx.x; i < GN; i += 256) {
        float avg = (float)counts[i] * (1.0f / (float)M_ROWS);
        sum += avg * logf(avg + 1e-7f);
    }
    red[threadIdx.x] = sum;
    __syncthreads();
    for (int s = 128; s > 0; s >>= 1) {
        if (threadIdx.x < s) red[threadIdx.x] += red[threadIdx.x + s];
        __syncthreads();
    }
    if (threadIdx.x == 0) out_loss[0] = -red[0] * (1.0f / (float)NGRP);
}

extern "C" void kernel_launch(void* const* d_in, const int* in_sizes, int n_in,
                              void* d_out, int out_size, void* d_ws, size_t ws_size,
                              hipStream_t stream) {
    const float* x        = (const float*)d_in[0];
    const float* gumbel   = (const float*)d_in[1];
    const float* codebook = (const float*)d_in[2];
    const float* W        = (const float*)d_in[3];
    const float* bias     = (const float*)d_in[4];
    float* out = (float*)d_out;

    unsigned short* Wt = (unsigned short*)d_ws;                       // 640*1024*2 B
    int* counts = (int*)((char*)d_ws + (size_t)GN * KDIM * 2 + 256);  // 640 ints

    wt_kernel<<<dim3(GN / 32, KDIM / 32), dim3(256), 0, stream>>>(W, Wt);
    zero_counts<<<dim3(3), dim3(256), 0, stream>>>(counts);
    gemm_argmax_gather<<<dim3(M_ROWS / BM), dim3(256), 0, stream>>>(
        x, gumbel, codebook, Wt, bias, out, counts);
    loss_kernel<<<dim3(1), dim3(256), 0, stream>>>(
        counts, out + (size_t)M_ROWS * KDIM);
}

// Round 3
// 160.449 us; speedup vs baseline: 4.8276x; 1.3755x over previous
//
#include <hip/hip_runtime.h>
#include <math.h>

// Problem constants (B=8, T=4096, D=1024, G=2, N=320, Cd=512)
#define M_ROWS 32768   // B*T
#define KDIM   1024    // D
#define GN     640     // G*N
#define NGRP   2
#define NCODES 320
#define CD     512

#define BM 64          // rows per block
#define BK 32          // k-tile
#define NT (KDIM / BK) // 32
#define THREADS 512    // 8 waves: 2 (M) x 4 (N)

#define B_TILE_BYTES (4 * GN * 16)   // 40960: [ks(4)][c(640)][16B]
#define A_TILE_BYTES (4 * BM * 16)   // 4096:  [ks(4)][row(64)][16B]

typedef __attribute__((ext_vector_type(8))) short bf16x8;   // 8 bf16 = 4 VGPR
typedef __attribute__((ext_vector_type(4))) float f32x4;

__device__ __forceinline__ unsigned short f2bf(float f) {
    unsigned u = __builtin_bit_cast(unsigned, f);
    return (unsigned short)((u + 0x7FFFu + ((u >> 16) & 1u)) >> 16);  // RNE
}
__device__ __forceinline__ unsigned pk2(float lo, float hi) {
    return (unsigned)f2bf(lo) | ((unsigned)f2bf(hi) << 16);
}

// async global->LDS, 16B per lane; LDS dest = uniform base + lane*16 (HW rule)
__device__ __forceinline__ void gll16(const void* g, void* l) {
    __builtin_amdgcn_global_load_lds(
        (const __attribute__((address_space(1))) unsigned int*)g,
        (__attribute__((address_space(3))) unsigned int*)l, 16, 0, 0);
}

// ---- prepass: W[k][GN] fp32 -> Wt2 bf16 tiled EXACTLY as the per-tile LDS layout:
// Wt2[t][ks][c][j], t=k>>5, ks=(k>>3)&3, j=k&7. One 40 KB slab per k-tile, linear.
__global__ __launch_bounds__(256) void wt2_kernel(const float* __restrict__ W,
                                                  unsigned short* __restrict__ Wt2) {
    const int k = blockIdx.x;                    // 0..1023
    const int t = k >> 5, ks = (k >> 3) & 3, j = k & 7;
    const size_t obase = (((size_t)t * 4 + ks) * GN) * 8 + j;
    for (int c = threadIdx.x; c < GN; c += 256)
        Wt2[obase + (size_t)c * 8] = f2bf(W[(size_t)k * GN + c]);
}

__global__ void zero_counts(int* __restrict__ counts) {
    int i = threadIdx.x + blockIdx.x * blockDim.x;
    if (i < GN) counts[i] = 0;
}

// ---- fused MFMA GEMM + argmax + gather, LDS-staged B via global_load_lds
__global__ __launch_bounds__(THREADS) void gemm_argmax_gather(
    const float* __restrict__ x,              // [M, K] fp32
    const float* __restrict__ gumbel,         // [M, GN] fp32
    const float* __restrict__ codebook,       // [G, N, CD] fp32
    const unsigned short* __restrict__ Wt2,   // retiled bf16 (see wt2_kernel)
    const float* __restrict__ bias,           // [GN]
    float* __restrict__ out,                  // [M, G*CD] fp32 (+ loss slot)
    int* __restrict__ counts)                 // [GN]
{
    __shared__ __align__(16) unsigned short Bs[2][4][GN][8];  // 80 KB
    __shared__ __align__(16) unsigned short As[2][4][BM][8];  // 8 KB
    __shared__ float pv[NGRP][2][BM];
    __shared__ int   pi[NGRP][2][BM];
    __shared__ int   idx_s[NGRP][BM];

    const int tid  = threadIdx.x;
    const int widx = tid >> 6;       // 0..7
    const int lane = tid & 63;
    const int l15  = lane & 15;
    const int l4   = lane >> 4;      // 0..3 (k-slot)
    const int wn   = widx & 3;       // column quarter: cols wn*160..wn*160+159
    const int wm   = widx >> 2;      // row half: rows wm*32..wm*32+31
    const int row0 = blockIdx.x * BM;

    f32x4 acc[2][10];
#pragma unroll
    for (int mf = 0; mf < 2; ++mf)
#pragma unroll
        for (int nf = 0; nf < 10; ++nf) acc[mf][nf] = (f32x4){0.f, 0.f, 0.f, 0.f};

    // A staging geometry: thread -> (row, 4-fp32 quad)
    const int arow = tid >> 3;       // 0..63
    const int aq   = tid & 7;        // quad: k = aq*4..aq*4+3
    const float* axsrc = &x[(size_t)(row0 + arow) * KDIM + aq * 4];
    // B staging: 40 slabs of 1KB; wave w handles slabs w*5..w*5+4
    const char* bsrc = (const char*)Wt2 + (size_t)(widx * 5) * 1024 + (size_t)lane * 16;
    char* Bs0 = (char*)&Bs[0][0][0][0];
    char* As0 = (char*)&As[0][0][0][0];

    // ---- prologue: stage tile 0
    {
        float4 av = *reinterpret_cast<const float4*>(axsrc);
#pragma unroll
        for (int i = 0; i < 5; ++i)
            gll16(bsrc + i * 1024, Bs0 + (widx * 5 + i) * 1024);
        uint2 w2 = { pk2(av.x, av.y), pk2(av.z, av.w) };
        *reinterpret_cast<uint2*>(As0 + (aq >> 1) * (BM * 16) + arow * 16 + (aq & 1) * 8) = w2;
    }
    __syncthreads();   // implicit vmcnt(0)+lgkmcnt(0) drain: tile 0 ready

    for (int t = 0; t < NT; ++t) {
        const int buf = t & 1;
        // issue next tile's loads first (hide under MFMA)
        float4 av;
        if (t + 1 < NT) {
            av = *reinterpret_cast<const float4*>(axsrc + (size_t)(t + 1) * BK);
#pragma unroll
            for (int i = 0; i < 5; ++i)
                gll16(bsrc + (size_t)(t + 1) * B_TILE_BYTES + i * 1024,
                      Bs0 + (buf ^ 1) * B_TILE_BYTES + (widx * 5 + i) * 1024);
        }
        // compute on current tile
        bf16x8 afr[2];
#pragma unroll
        for (int mf = 0; mf < 2; ++mf)
            afr[mf] = *reinterpret_cast<const bf16x8*>(
                As0 + buf * A_TILE_BYTES + l4 * (BM * 16) + (wm * 32 + mf * 16 + l15) * 16);
#pragma unroll
        for (int nf = 0; nf < 10; ++nf) {
            bf16x8 bfr = *reinterpret_cast<const bf16x8*>(
                Bs0 + buf * B_TILE_BYTES + l4 * (GN * 16) + (wn * 160 + nf * 16 + l15) * 16);
            acc[0][nf] = __builtin_amdgcn_mfma_f32_16x16x32_bf16(afr[0], bfr, acc[0][nf], 0, 0, 0);
            acc[1][nf] = __builtin_amdgcn_mfma_f32_16x16x32_bf16(afr[1], bfr, acc[1][nf], 0, 0, 0);
        }
        // write next A tile (its buffer was last read before the previous barrier)
        if (t + 1 < NT) {
            uint2 w2 = { pk2(av.x, av.y), pk2(av.z, av.w) };
            *reinterpret_cast<uint2*>(As0 + (buf ^ 1) * A_TILE_BYTES +
                                      (aq >> 1) * (BM * 16) + arow * 16 + (aq & 1) * 8) = w2;
        }
        __syncthreads();   // drains vmcnt: next tile's B is in LDS
    }

    // ---- epilogue: + bias + gumbel, argmax per row over this wave's 160 cols
    // C/D layout: col = l15, row-in-frag = l4*4 + reg
#pragma unroll
    for (int mf = 0; mf < 2; ++mf) {
#pragma unroll
        for (int j = 0; j < 4; ++j) {
            const int lr = wm * 32 + mf * 16 + l4 * 4 + j;
            const size_t grow = (size_t)(row0 + lr) * GN;
            float best = -INFINITY;
            int bidx = 0;
#pragma unroll
            for (int nf = 0; nf < 10; ++nf) {
                int c = wn * 160 + nf * 16 + l15;
                float v = acc[mf][nf][j] + bias[c] + gumbel[grow + c];
                if (v > best) { best = v; bidx = c; }   // nf ascending -> first max kept
            }
#pragma unroll
            for (int m = 1; m < 16; m <<= 1) {
                float ov = __shfl_xor(best, m, 64);
                int   oi = __shfl_xor(bidx, m, 64);
                if (ov > best || (ov == best && oi < bidx)) { best = ov; bidx = oi; }
            }
            if (l15 == 0) {
                pv[wn >> 1][wn & 1][lr] = best;
                pi[wn >> 1][wn & 1][lr] = bidx;
            }
        }
    }
    __syncthreads();

    // combine the two column-halves per group; half 1's cols all > half 0's,
    // so strict > keeps the lower index on ties (matches np.argmax).
    if (tid < NGRP * BM) {
        const int g = tid >> 6, lr = tid & 63;
        float v0 = pv[g][0][lr], v1 = pv[g][1][lr];
        int   i0 = pi[g][0][lr], i1 = pi[g][1][lr];
        int bi = (v1 > v0) ? i1 : i0;
        int n  = bi - g * NCODES;
        idx_s[g][lr] = n;
        atomicAdd(&counts[g * NCODES + n], 1);
    }
    __syncthreads();

    // ---- gather: 64 rows x 256 float4, coalesced writes
#pragma unroll
    for (int s = 0; s < 32; ++s) {
        int fi = tid + THREADS * s;   // 0..16383
        int lr = fi >> 8;             // /256 float4 per row
        int q  = fi & 255;
        int g  = q >> 7;
        int n  = idx_s[g][lr];
        float4 cv = *reinterpret_cast<const float4*>(
            &codebook[((size_t)g * NCODES + n) * CD + (q & 127) * 4]);
        *reinterpret_cast<float4*>(&out[(size_t)(row0 + lr) * KDIM + q * 4]) = cv;
    }
}

__global__ void loss_kernel(const int* __restrict__ counts, float* __restrict__ out_loss) {
    __shared__ float red[256];
    float sum = 0.0f;
    for (int i = threadIdx.x; i < GN; i += 256) {
        float avg = (float)counts[i] * (1.0f / (float)M_ROWS);
        sum += avg * logf(avg + 1e-7f);
    }
    red[threadIdx.x] = sum;
    __syncthreads();
    for (int s = 128; s > 0; s >>= 1) {
        if (threadIdx.x < s) red[threadIdx.x] += red[threadIdx.x + s];
        __syncthreads();
    }
    if (threadIdx.x == 0) out_loss[0] = -red[0] * (1.0f / (float)NGRP);
}

extern "C" void kernel_launch(void* const* d_in, const int* in_sizes, int n_in,
                              void* d_out, int out_size, void* d_ws, size_t ws_size,
                              hipStream_t stream) {
    const float* x        = (const float*)d_in[0];
    const float* gumbel   = (const float*)d_in[1];
    const float* codebook = (const float*)d_in[2];
    const float* W        = (const float*)d_in[3];
    const float* bias     = (const float*)d_in[4];
    float* out = (float*)d_out;

    unsigned short* Wt2 = (unsigned short*)d_ws;                      // 1.25 MB retiled
    int* counts = (int*)((char*)d_ws + (size_t)GN * KDIM * 2 + 256);  // 640 ints

    wt2_kernel<<<dim3(KDIM), dim3(256), 0, stream>>>(W, Wt2);
    zero_counts<<<dim3(3), dim3(256), 0, stream>>>(counts);
    gemm_argmax_gather<<<dim3(M_ROWS / BM), dim3(THREADS), 0, stream>>>(
        x, gumbel, codebook, Wt2, bias, out, counts);
    loss_kernel<<<dim3(1), dim3(256), 0, stream>>>(
        counts, out + (size_t)M_ROWS * KDIM);
}

// Round 4
// 126.160 us; speedup vs baseline: 6.1398x; 1.2718x over previous
//
#include <hip/hip_runtime.h>
#include <math.h>

// Problem constants (B=8, T=4096, D=1024, G=2, N=320, Cd=512)
#define M_ROWS 32768   // B*T
#define KDIM   1024    // D
#define GN     640     // G*N
#define NGRP   2
#define NCODES 320
#define CD     512

#define BM 64          // rows per block
#define BK 32          // k-tile
#define NT (KDIM / BK) // 32
#define THREADS 512    // 8 waves: 2 (M) x 4 (N)

#define B_TILE_BYTES (4 * GN * 16)   // 40960 per k-tile slab in Wt2

typedef __attribute__((ext_vector_type(8))) short bf16x8;   // 8 bf16 = 4 VGPR
typedef __attribute__((ext_vector_type(4))) float f32x4;

__device__ __forceinline__ unsigned short f2bf(float f) {
    unsigned u = __builtin_bit_cast(unsigned, f);
    return (unsigned short)((u + 0x7FFFu + ((u >> 16) & 1u)) >> 16);  // RNE
}
__device__ __forceinline__ unsigned pk2(float lo, float hi) {
    return (unsigned)f2bf(lo) | ((unsigned)f2bf(hi) << 16);
}

// async global->LDS, 16B per lane; LDS dest = wave-uniform base + lane*16
__device__ __forceinline__ void gll16(const void* g, void* l) {
    __builtin_amdgcn_global_load_lds(
        (const __attribute__((address_space(1))) unsigned int*)g,
        (__attribute__((address_space(3))) unsigned int*)l, 16, 0, 0);
}

// ---- prepass: W[k][GN] fp32 -> Wt2 bf16 tiled EXACTLY as the per-tile LDS layout:
// Wt2[t][ks][c][j], t=k>>5, ks=(k>>3)&3, j=k&7. One 40 KB slab per k-tile, linear.
// Also zeroes the counts histogram (block 0).
__global__ __launch_bounds__(256) void wt2_kernel(const float* __restrict__ W,
                                                  unsigned short* __restrict__ Wt2,
                                                  int* __restrict__ counts) {
    const int k = blockIdx.x;                    // 0..1023
    const int t = k >> 5, ks = (k >> 3) & 3, j = k & 7;
    const size_t obase = (((size_t)t * 4 + ks) * GN) * 8 + j;
    for (int c = threadIdx.x; c < GN; c += 256)
        Wt2[obase + (size_t)c * 8] = f2bf(W[(size_t)k * GN + c]);
    if (k == 0)
        for (int i = threadIdx.x; i < GN; i += 256) counts[i] = 0;
}

// ---- fused MFMA GEMM + argmax + gather; single-buffered DMA staging,
// 2 barriers per k-tile, ~51 KB LDS -> 2 blocks/CU for cross-block overlap.
__global__ __launch_bounds__(THREADS) void gemm_argmax_gather(
    const float* __restrict__ x,              // [M, K] fp32
    const float* __restrict__ gumbel,         // [M, GN] fp32
    const float* __restrict__ codebook,       // [G, N, CD] fp32
    const unsigned short* __restrict__ Wt2,   // retiled bf16 (see wt2_kernel)
    const float* __restrict__ bias,           // [GN]
    float* __restrict__ out,                  // [M, G*CD] fp32 (+ loss slot)
    int* __restrict__ counts)                 // [GN]
{
    __shared__ __align__(16) unsigned short Bs[4][GN][8];  // 40 KB, one k-tile
    __shared__ __align__(16) float As[BM][BK];             // 8 KB fp32, one k-tile
    __shared__ float pv[NGRP][2][BM];
    __shared__ int   pi[NGRP][2][BM];
    __shared__ int   idx_s[NGRP][BM];

    const int tid  = threadIdx.x;
    const int widx = tid >> 6;       // 0..7
    const int lane = tid & 63;
    const int l15  = lane & 15;
    const int l4   = lane >> 4;      // 0..3 (k-slot)
    const int wn   = widx & 3;       // column quarter: cols wn*160..wn*160+159
    const int wm   = widx >> 2;      // row half: rows wm*32..wm*32+31
    const int row0 = blockIdx.x * BM;

    f32x4 acc[2][10];
#pragma unroll
    for (int mf = 0; mf < 2; ++mf)
#pragma unroll
        for (int nf = 0; nf < 10; ++nf) acc[mf][nf] = (f32x4){0.f, 0.f, 0.f, 0.f};

    // B staging: 40 slabs of 1 KB; wave w handles slabs w*5..w*5+4 (linear copy)
    const char* bsrc = (const char*)Wt2 + (size_t)(widx * 5) * 1024 + (size_t)lane * 16;
    char* BsBase = (char*)&Bs[0][0][0];
    // A staging: wave w stages rows w*8..w*8+7 (1 KB), fp32, 16B subchunks.
    // Chunk-XOR swizzle lives in the per-lane GLOBAL source; LDS dest stays linear.
    const int arow = widx * 8 + (lane >> 3);     // local row 0..63
    const int asub = lane & 7;                   // 16B subchunk position in LDS row
    const int asg  = ((((asub >> 1) ^ (arow & 3)) << 1) | (asub & 1)); // global subchunk
    const char* asrc = (const char*)x + (size_t)(row0 + arow) * (KDIM * 4) + (size_t)asg * 16;
    char* AsBase = (char*)&As[0][0];
    char* adst   = AsBase + widx * 1024;         // + lane*16 implicit in DMA

    // ---- prologue: stage tile 0
#pragma unroll
    for (int i = 0; i < 5; ++i)
        gll16(bsrc + i * 1024, BsBase + (widx * 5 + i) * 1024);
    gll16(asrc, adst);
    __syncthreads();   // drains vmcnt: tile 0 resident

    for (int t = 0; t < NT; ++t) {
        // A fragments: read swizzled 32B fp32 chunk, convert to bf16x8
        bf16x8 afr[2];
#pragma unroll
        for (int mf = 0; mf < 2; ++mf) {
            const int row = wm * 32 + mf * 16 + l15;
            const int q   = l4 ^ (row & 3);              // inverse of source swizzle
            const float4* pa = reinterpret_cast<const float4*>(AsBase + row * 128 + q * 32);
            float4 a0 = pa[0], a1 = pa[1];
            union { bf16x8 v; unsigned u[4]; } w;
            w.u[0] = pk2(a0.x, a0.y); w.u[1] = pk2(a0.z, a0.w);
            w.u[2] = pk2(a1.x, a1.y); w.u[3] = pk2(a1.z, a1.w);
            afr[mf] = w.v;
        }
#pragma unroll
        for (int nf = 0; nf < 10; ++nf) {
            bf16x8 bfr = *reinterpret_cast<const bf16x8*>(
                BsBase + ((size_t)l4 * GN + wn * 160 + nf * 16 + l15) * 16);
            acc[0][nf] = __builtin_amdgcn_mfma_f32_16x16x32_bf16(afr[0], bfr, acc[0][nf], 0, 0, 0);
            acc[1][nf] = __builtin_amdgcn_mfma_f32_16x16x32_bf16(afr[1], bfr, acc[1][nf], 0, 0, 0);
        }
        __syncthreads();   // all waves done reading tile t
        if (t + 1 < NT) {
#pragma unroll
            for (int i = 0; i < 5; ++i)
                gll16(bsrc + (size_t)(t + 1) * B_TILE_BYTES + i * 1024,
                      BsBase + (widx * 5 + i) * 1024);
            gll16(asrc + (size_t)(t + 1) * 128, adst);
        }
        __syncthreads();   // drains DMA: tile t+1 resident
    }

    // ---- epilogue: + bias + gumbel, argmax per row over this wave's 160 cols
    // C/D layout: col = l15, row-in-frag = l4*4 + reg
#pragma unroll
    for (int mf = 0; mf < 2; ++mf) {
#pragma unroll
        for (int j = 0; j < 4; ++j) {
            const int lr = wm * 32 + mf * 16 + l4 * 4 + j;
            const size_t grow = (size_t)(row0 + lr) * GN;
            float best = -INFINITY;
            int bidx = 0;
#pragma unroll
            for (int nf = 0; nf < 10; ++nf) {
                int c = wn * 160 + nf * 16 + l15;
                float v = acc[mf][nf][j] + bias[c] + gumbel[grow + c];
                if (v > best) { best = v; bidx = c; }   // nf ascending -> first max kept
            }
#pragma unroll
            for (int m = 1; m < 16; m <<= 1) {
                float ov = __shfl_xor(best, m, 64);
                int   oi = __shfl_xor(bidx, m, 64);
                if (ov > best || (ov == best && oi < bidx)) { best = ov; bidx = oi; }
            }
            if (l15 == 0) {
                pv[wn >> 1][wn & 1][lr] = best;
                pi[wn >> 1][wn & 1][lr] = bidx;
            }
        }
    }
    __syncthreads();

    // combine the two column-halves per group; half 1's cols all > half 0's,
    // so strict > keeps the lower index on ties (matches np.argmax).
    if (tid < NGRP * BM) {
        const int g = tid >> 6, lr = tid & 63;
        float v0 = pv[g][0][lr], v1 = pv[g][1][lr];
        int   i0 = pi[g][0][lr], i1 = pi[g][1][lr];
        int bi = (v1 > v0) ? i1 : i0;
        int n  = bi - g * NCODES;
        idx_s[g][lr] = n;
        atomicAdd(&counts[g * NCODES + n], 1);
    }
    __syncthreads();

    // ---- gather: 64 rows x 256 float4, coalesced writes
#pragma unroll
    for (int s = 0; s < 32; ++s) {
        int fi = tid + THREADS * s;   // 0..16383
        int lr = fi >> 8;             // /256 float4 per row
        int q  = fi & 255;
        int g  = q >> 7;
        int n  = idx_s[g][lr];
        float4 cv = *reinterpret_cast<const float4*>(
            &codebook[((size_t)g * NCODES + n) * CD + (q & 127) * 4]);
        *reinterpret_cast<float4*>(&out[(size_t)(row0 + lr) * KDIM + q * 4]) = cv;
    }
}

__global__ void loss_kernel(const int* __restrict__ counts, float* __restrict__ out_loss) {
    __shared__ float red[256];
    float sum = 0.0f;
    for (int i = threadIdx.x; i < GN; i += 256) {
        float avg = (float)counts[i] * (1.0f / (float)M_ROWS);
        sum += avg * logf(avg + 1e-7f);
    }
    red[threadIdx.x] = sum;
    __syncthreads();
    for (int s = 128; s > 0; s >>= 1) {
        if (threadIdx.x < s) red[threadIdx.x] += red[threadIdx.x + s];
        __syncthreads();
    }
    if (threadIdx.x == 0) out_loss[0] = -red[0] * (1.0f / (float)NGRP);
}

extern "C" void kernel_launch(void* const* d_in, const int* in_sizes, int n_in,
                              void* d_out, int out_size, void* d_ws, size_t ws_size,
                              hipStream_t stream) {
    const float* x        = (const float*)d_in[0];
    const float* gumbel   = (const float*)d_in[1];
    const float* codebook = (const float*)d_in[2];
    const float* W        = (const float*)d_in[3];
    const float* bias     = (const float*)d_in[4];
    float* out = (float*)d_out;

    unsigned short* Wt2 = (unsigned short*)d_ws;                      // 1.25 MB retiled
    int* counts = (int*)((char*)d_ws + (size_t)GN * KDIM * 2 + 256);  // 640 ints

    wt2_kernel<<<dim3(KDIM), dim3(256), 0, stream>>>(W, Wt2, counts);
    gemm_argmax_gather<<<dim3(M_ROWS / BM), dim3(THREADS), 0, stream>>>(
        x, gumbel, codebook, Wt2, bias, out, counts);
    loss_kernel<<<dim3(1), dim3(256), 0, stream>>>(
        counts, out + (size_t)M_ROWS * KDIM);
}